// Round 12
// baseline (437.977 us; speedup 1.0000x reference)
//
#include <hip/hip_runtime.h>
#include <hip/hip_bf16.h>

#define DIM 1024
#define SEQ 2048
#define BATCH 4
#define HEADS 16
#define DHEAD 64
#define ROWS (BATCH * SEQ)   // 8192
#define QKV_N (3 * DIM)      // 3072

typedef __attribute__((ext_vector_type(4))) float f32x4;
typedef __attribute__((ext_vector_type(8))) short s16x8;   // 8 bf16 in 4 VGPRs

__device__ __forceinline__ unsigned short f2bf(float f) {
  union { __hip_bfloat16 h; unsigned short u; } c;
  c.h = __float2bfloat16(f);
  return c.u;
}

// packed f32x2 -> bf16x2 (dst.lo = cvt(a), dst.hi = cvt(b))
__device__ __forceinline__ unsigned cvtpk(float a, float b) {
  unsigned r;
  asm("v_cvt_pk_bf16_f32 %0, %1, %2" : "=v"(r) : "v"(a), "v"(b));
  return r;
}

__device__ __forceinline__ void gl_lds16(const void* g, void* l) {
  __builtin_amdgcn_global_load_lds(
      (const __attribute__((address_space(1))) unsigned int*)g,
      (__attribute__((address_space(3))) unsigned int*)l, 16, 0, 0);
}

// ---------------- LayerNorm (fp32 in, bf16 out) ----------------
__global__ __launch_bounds__(256) void ln_bf16(const float* __restrict__ x,
                                               const float* __restrict__ g,
                                               const float* __restrict__ beta,
                                               unsigned short* __restrict__ xn) {
  const int row = blockIdx.x;
  const int tid = threadIdx.x;
  float4 v = ((const float4*)(x + (size_t)row * DIM))[tid];
  float s  = v.x + v.y + v.z + v.w;
  float ss = v.x * v.x + v.y * v.y + v.z * v.z + v.w * v.w;
#pragma unroll
  for (int off = 32; off > 0; off >>= 1) {
    s  += __shfl_down(s, off);
    ss += __shfl_down(ss, off);
  }
  __shared__ float red[8];
  const int wid = tid >> 6;
  if ((tid & 63) == 0) { red[wid] = s; red[4 + wid] = ss; }
  __syncthreads();
  if (tid == 0) {
    red[0] = red[0] + red[1] + red[2] + red[3];
    red[4] = red[4] + red[5] + red[6] + red[7];
  }
  __syncthreads();
  const float mu   = red[0] * (1.0f / DIM);
  const float var  = red[4] * (1.0f / DIM) - mu * mu;
  const float rstd = rsqrtf(var + 1e-5f);
  float4 gg = ((const float4*)g)[tid];
  float4 bb = ((const float4*)beta)[tid];
  ushort4 o;
  o.x = f2bf((v.x - mu) * rstd * gg.x + bb.x);
  o.y = f2bf((v.y - mu) * rstd * gg.y + bb.y);
  o.z = f2bf((v.z - mu) * rstd * gg.z + bb.z);
  o.w = f2bf((v.w - mu) * rstd * gg.w + bb.w);
  ((ushort4*)(xn + (size_t)row * DIM))[tid] = o;
}

// ------------- weight transpose fp32 [K][N] -> bf16 [N][K] -------------
// Rows n < qcols are scaled by qscale (folds softmax scale into Q-columns).
__global__ __launch_bounds__(256) void transpose_w(const float* __restrict__ W,
                                                   unsigned short* __restrict__ Wt,
                                                   int Kd, int Nd,
                                                   int qcols, float qscale) {
  __shared__ float T[64][65];
  const int t = threadIdx.x;
  const int n0 = blockIdx.x * 64, k0 = blockIdx.y * 64;
#pragma unroll
  for (int r = 0; r < 4; r++) {
    int gidx = t + r * 256;           // 0..1023 float4 granules
    int row = gidx >> 4, c4 = (gidx & 15) << 2;
    float4 v = *(const float4*)(W + (size_t)(k0 + row) * Nd + n0 + c4);
    T[row][c4 + 0] = v.x; T[row][c4 + 1] = v.y;
    T[row][c4 + 2] = v.z; T[row][c4 + 3] = v.w;
  }
  __syncthreads();
#pragma unroll
  for (int r = 0; r < 2; r++) {
    int gidx = t + r * 256;           // 0..511 8-elt bf16 granules
    int nrow = gidx >> 3, cs = (gidx & 7) << 3;
    float sc = (n0 + nrow < qcols) ? qscale : 1.0f;
    s16x8 o;
#pragma unroll
    for (int j = 0; j < 8; j++) o[j] = (short)f2bf(T[cs + j][nrow] * sc);
    *(s16x8*)(Wt + (size_t)(n0 + nrow) * Kd + k0 + cs) = o;
  }
}

// ------------- V transpose: qkv bf16 [b,seq,3072] V-part -> Vt [b,h,64,SEQ] -------------
__global__ __launch_bounds__(256) void transpose_v(const unsigned short* __restrict__ qkv,
                                                   unsigned short* __restrict__ vt) {
  __shared__ unsigned short T[64][72];
  const int t = threadIdx.x;
  const int s0 = blockIdx.x * 64;
  const int bh = blockIdx.y, b = bh >> 4, h = bh & 15;
#pragma unroll
  for (int r = 0; r < 2; r++) {
    int g = t + r * 256;
    int row = g >> 3, c = (g & 7) << 3;
    s16x8 v = *(const s16x8*)(qkv + ((size_t)(b * SEQ + s0 + row)) * QKV_N + 2 * DIM + h * DHEAD + c);
    *(s16x8*)(&T[row][c]) = v;
  }
  __syncthreads();
#pragma unroll
  for (int r = 0; r < 2; r++) {
    int g = t + r * 256;
    int drow = g >> 3, sc = (g & 7) << 3;
    s16x8 o;
#pragma unroll
    for (int j = 0; j < 8; j++) o[j] = (short)T[sc + j][drow];
    *(s16x8*)(vt + ((size_t)(bh * DHEAD + drow)) * SEQ + s0 + sc) = o;
  }
}

// ------------- bf16 MFMA GEMM: C[M,N] = A[M,K] * Bt[N,K]^T (+bias) -------------
template <bool OUT_BF16, bool BIAS>
__global__ __launch_bounds__(256) void gemm_bt_bf16(const unsigned short* __restrict__ A,
                                                    const unsigned short* __restrict__ Bt,
                                                    const float* __restrict__ bias,
                                                    void* __restrict__ Cv,
                                                    int M, int N, int K) {
  __shared__ unsigned short As[2][128 * 32];
  __shared__ unsigned short Bs[2][128 * 32];
  const int tid = threadIdx.x;
  const int w = tid >> 6, l = tid & 63;
  const int lr = l & 15, lg = l >> 4;
  const int wr = w >> 1, wc = w & 1;

  const int nbx = N >> 7;
  const int nwg = nbx * (M >> 7);
  int bid = blockIdx.y * nbx + blockIdx.x;
  int swz = (bid & 7) * (nwg >> 3) + (bid >> 3);   // XCD-aware (nwg % 8 == 0)
  const int bx = swz % nbx, by = swz / nbx;
  const int m0 = by << 7, n0 = bx << 7;

  auto stage = [&](int k0, int buf) {
#pragma unroll
    for (int c = 0; c < 2; c++) {
      int gidx = tid + c * 256;               // 0..511 granules (16B)
      int row = gidx >> 2, sl = gidx & 3;
      int ss = sl ^ ((row ^ (row >> 2)) & 3);
      gl_lds16(A  + (size_t)(m0 + row) * K + k0 + ss * 8, &As[buf][gidx * 8]);
      gl_lds16(Bt + (size_t)(n0 + row) * K + k0 + ss * 8, &Bs[buf][gidx * 8]);
    }
  };

  f32x4 acc[4][4];
#pragma unroll
  for (int mi = 0; mi < 4; mi++)
#pragma unroll
    for (int ni = 0; ni < 4; ni++) acc[mi][ni] = (f32x4){0.f, 0.f, 0.f, 0.f};

  const int NT = K >> 5;
  stage(0, 0);
  int cur = 0;
  for (int t = 0; t < NT; t++) {
    __syncthreads();
    if (t + 1 < NT) stage((t + 1) << 5, cur ^ 1);
    s16x8 af[4], bfr[4];
#pragma unroll
    for (int mi = 0; mi < 4; mi++) {
      int rowa = wr * 64 + mi * 16 + lr;
      int sla = lg ^ ((rowa ^ (rowa >> 2)) & 3);
      af[mi] = *(const s16x8*)&As[cur][rowa * 32 + sla * 8];
      int rowb = wc * 64 + mi * 16 + lr;
      int slb = lg ^ ((rowb ^ (rowb >> 2)) & 3);
      bfr[mi] = *(const s16x8*)&Bs[cur][rowb * 32 + slb * 8];
    }
#pragma unroll
    for (int mi = 0; mi < 4; mi++)
#pragma unroll
      for (int ni = 0; ni < 4; ni++)
        acc[mi][ni] = __builtin_amdgcn_mfma_f32_16x16x32_bf16(af[mi], bfr[ni], acc[mi][ni], 0, 0, 0);
    cur ^= 1;
  }

#pragma unroll
  for (int mi = 0; mi < 4; mi++) {
#pragma unroll
    for (int ni = 0; ni < 4; ni++) {
      int col = n0 + wc * 64 + ni * 16 + lr;
      float bv = BIAS ? bias[col] : 0.f;
#pragma unroll
      for (int i = 0; i < 4; i++) {
        size_t rowg = (size_t)m0 + wr * 64 + mi * 16 + lg * 4 + i;
        float vv = acc[mi][ni][i] + bv;
        if (OUT_BF16) ((unsigned short*)Cv)[rowg * N + col] = f2bf(vv);
        else          ((float*)Cv)[rowg * N + col] = vv;
      }
    }
  }
}

// ------------- flash attention, bf16 MFMA, direct-reg K/V, no barriers ------
// grid (SEQ/128, BATCH*HEADS), 256 thr = 4 independent waves; wave w owns 32
// q-rows as two 16-row fragments. K and V^T fragments are per-lane CONTIGUOUS
// 16B global loads with tile-invariant voffsets (only uniform base bumps per
// tile) -> no K/V LDS, no staging, no barriers, no swizzle addressing.
// K(t+1) prefetch rotates kfA/kfB (static names, rule #20); V(t) issues before
// softmax so the exp chain hides L2 latency. Q pre-scaled by 0.125*log2(e).
// Bijective XCD swizzle: each XCD gets 8 bh (4MB K/V = L2-resident).
// Ps (P roundtrip) stride 68 shorts: conflict-free (R7-measured 0).
__global__ __launch_bounds__(256) void attn_mfma(const unsigned short* __restrict__ qkv,
                                                 const unsigned short* __restrict__ vt,
                                                 unsigned short* __restrict__ aout) {
  __shared__ unsigned short Ps[4][32 * 68];
  const int tid = threadIdx.x;
  const int w = tid >> 6, l = tid & 63;
  const int lr = l & 15, lg = l >> 4;
  // XCD swizzle: 1024 blocks, XCD c <- works c*128..c*128+127 = bh c*8..c*8+7
  const int bid = blockIdx.y * (SEQ / 128) + blockIdx.x;
  const int swz = (bid & 7) * 128 + (bid >> 3);
  const int qt = swz & 15, bh = swz >> 4;
  const int b = bh >> 4, h = bh & 15;
  const size_t qrow0 = (size_t)b * SEQ + qt * 128;

  const unsigned short* kb = qkv + ((size_t)b * SEQ) * QKV_N + DIM + h * DHEAD;
  const unsigned short* vb = vt + (size_t)bh * DHEAD * SEQ;
  const int kvo = lr * QKV_N + lg * 8;   // per-lane K voffset (tile-invariant)
  const int vvo = lr * SEQ + lg * 8;     // per-lane Vt voffset (tile-invariant)

  // Q fragments direct from global: Q[w*32+rf*16+lr][s*32+lg*8..+7]
  s16x8 qf[2][2];
  {
    const unsigned short* qb = qkv + (qrow0 + (size_t)w * 32) * QKV_N + h * DHEAD;
#pragma unroll
    for (int rf = 0; rf < 2; rf++)
#pragma unroll
      for (int s = 0; s < 2; s++)
        qf[rf][s] = *(const s16x8*)(qb + (rf * 16 + lr) * QKV_N + s * 32 + lg * 8);
  }

  // K(0) into kfA
  s16x8 kfA[4][2], kfB[4][2];
#pragma unroll
  for (int ni = 0; ni < 4; ni++)
#pragma unroll
    for (int kk = 0; kk < 2; kk++)
      kfA[ni][kk] = *(const s16x8*)(kb + kvo + ni * 16 * QKV_N + kk * 32);

  float lsum0 = 0.f, lsum1 = 0.f;
  f32x4 of[2][4];
#pragma unroll
  for (int rf = 0; rf < 2; rf++)
#pragma unroll
    for (int ni = 0; ni < 4; ni++) of[rf][ni] = (f32x4){0.f, 0.f, 0.f, 0.f};

  const int NT = SEQ / 64;  // 32

  auto tile = [&](int t, s16x8 (&kc)[4][2], s16x8 (&kn)[4][2]) {
    // S^T = K Q^T from registers
    f32x4 stf[2][4];
    __builtin_amdgcn_s_setprio(1);
#pragma unroll
    for (int ni = 0; ni < 4; ni++) {
      stf[0][ni] = __builtin_amdgcn_mfma_f32_16x16x32_bf16(kc[ni][0], qf[0][0], (f32x4){0.f, 0.f, 0.f, 0.f}, 0, 0, 0);
      stf[1][ni] = __builtin_amdgcn_mfma_f32_16x16x32_bf16(kc[ni][0], qf[1][0], (f32x4){0.f, 0.f, 0.f, 0.f}, 0, 0, 0);
      stf[0][ni] = __builtin_amdgcn_mfma_f32_16x16x32_bf16(kc[ni][1], qf[0][1], stf[0][ni], 0, 0, 0);
      stf[1][ni] = __builtin_amdgcn_mfma_f32_16x16x32_bf16(kc[ni][1], qf[1][1], stf[1][ni], 0, 0, 0);
    }
    __builtin_amdgcn_s_setprio(0);

    // issue V(t) loads (latency hidden under softmax)
    s16x8 vf[4][2];
    {
      const unsigned short* vbt = vb + t * 64;
#pragma unroll
      for (int ni = 0; ni < 4; ni++)
#pragma unroll
        for (int ks = 0; ks < 2; ks++)
          vf[ni][ks] = *(const s16x8*)(vbt + vvo + ni * 16 * SEQ + ks * 32);
    }
    // issue K(t+1) prefetch into kn (latency hidden under softmax+PV)
    if (t + 1 < NT) {
      const unsigned short* kbt = kb + (size_t)(t + 1) * 64 * QKV_N;
#pragma unroll
      for (int ni = 0; ni < 4; ni++)
#pragma unroll
        for (int kk = 0; kk < 2; kk++)
          kn[ni][kk] = *(const s16x8*)(kbt + kvo + ni * 16 * QKV_N + kk * 32);
    }

    // p = exp2(stf) (Q pre-scaled); per-lane partial sums
#pragma unroll
    for (int ni = 0; ni < 4; ni++)
#pragma unroll
      for (int i = 0; i < 4; i++) {
        float p0 = exp2f(stf[0][ni][i]);
        float p1 = exp2f(stf[1][ni][i]);
        stf[0][ni][i] = p0; lsum0 += p0;
        stf[1][ni][i] = p1; lsum1 += p1;
      }

    // pack P -> LDS (per-wave region; rows rf*16+lr, stride 68, slot swizzle)
#pragma unroll
    for (int rf = 0; rf < 2; rf++)
#pragma unroll
      for (int ni = 0; ni < 4; ni++) {
        uint2 pw;
        pw.x = cvtpk(stf[rf][ni][0], stf[rf][ni][1]);
        pw.y = cvtpk(stf[rf][ni][2], stf[rf][ni][3]);
        int sl = (ni * 4 + lg) ^ ((lr & 7) << 1);
        *(uint2*)&Ps[w][(rf * 16 + lr) * 68 + sl * 4] = pw;
      }

    // read P as B-frags
    s16x8 pf[2][2];
#pragma unroll
    for (int rf = 0; rf < 2; rf++)
#pragma unroll
      for (int ks = 0; ks < 2; ks++) {
        int sl0 = (ks * 8 + lg * 2) ^ ((lr & 7) << 1);
        int base = (rf * 16 + lr) * 68;
        uint2 pa = *(const uint2*)&Ps[w][base + sl0 * 4];
        uint2 pb = *(const uint2*)&Ps[w][base + (sl0 + 1) * 4];
        union { unsigned u[4]; s16x8 v; } U;
        U.u[0] = pa.x; U.u[1] = pa.y; U.u[2] = pb.x; U.u[3] = pb.y;
        pf[rf][ks] = U.v;
      }

    // O^T += V^T P^T from registers
    __builtin_amdgcn_s_setprio(1);
#pragma unroll
    for (int ni = 0; ni < 4; ni++) {
      of[0][ni] = __builtin_amdgcn_mfma_f32_16x16x32_bf16(vf[ni][0], pf[0][0], of[0][ni], 0, 0, 0);
      of[1][ni] = __builtin_amdgcn_mfma_f32_16x16x32_bf16(vf[ni][0], pf[1][0], of[1][ni], 0, 0, 0);
      of[0][ni] = __builtin_amdgcn_mfma_f32_16x16x32_bf16(vf[ni][1], pf[0][1], of[0][ni], 0, 0, 0);
      of[1][ni] = __builtin_amdgcn_mfma_f32_16x16x32_bf16(vf[ni][1], pf[1][1], of[1][ni], 0, 0, 0);
    }
    __builtin_amdgcn_s_setprio(0);
  };

  for (int t = 0; t < NT; t += 2) {
    tile(t, kfA, kfB);
    tile(t + 1, kfB, kfA);
  }

  // cross-lane lsum reduce (lanes l, l^16, l^32, l^48 share q-row)
  lsum0 += __shfl_xor(lsum0, 16);
  lsum0 += __shfl_xor(lsum0, 32);
  lsum1 += __shfl_xor(lsum1, 16);
  lsum1 += __shfl_xor(lsum1, 32);

  // epilogue
#pragma unroll
  for (int rf = 0; rf < 2; rf++) {
    float inv = 1.0f / (rf ? lsum1 : lsum0);
    size_t rowg = qrow0 + w * 32 + rf * 16 + lr;
#pragma unroll
    for (int ni = 0; ni < 4; ni++) {
      uint2 ov;
      ov.x = cvtpk(of[rf][ni][0] * inv, of[rf][ni][1] * inv);
      ov.y = cvtpk(of[rf][ni][2] * inv, of[rf][ni][3] * inv);
      *(uint2*)&aout[rowg * DIM + h * DHEAD + ni * 16 + lg * 4] = ov;
    }
  }
}

extern "C" void kernel_launch(void* const* d_in, const int* in_sizes, int n_in,
                              void* d_out, int out_size, void* d_ws, size_t ws_size,
                              hipStream_t stream) {
  const float* x     = (const float*)d_in[0];
  const float* ln_g  = (const float*)d_in[1];
  const float* ln_b  = (const float*)d_in[2];
  const float* w_qkv = (const float*)d_in[3];
  const float* w_out = (const float*)d_in[4];
  const float* b_out = (const float*)d_in[5];
  float* outp = (float*)d_out;

  char* ws = (char*)d_ws;
  unsigned short* xn      = (unsigned short*)(ws);                 // 16 MB
  unsigned short* qkv     = (unsigned short*)(ws + (16ull << 20)); // 48 MB
  unsigned short* vtb     = (unsigned short*)(ws + (64ull << 20)); // 16 MB
  unsigned short* aout    = (unsigned short*)(ws + (80ull << 20)); // 16 MB
  unsigned short* wt_qkv  = (unsigned short*)(ws + (96ull << 20)); // 6 MB
  unsigned short* wt_out  = (unsigned short*)(ws + (104ull << 20));// 2 MB

  const float CEXP = 0.18033688011112042f;  // 0.125 * log2(e), folded into Wq

  ln_bf16<<<ROWS, 256, 0, stream>>>(x, ln_g, ln_b, xn);
  transpose_w<<<dim3(QKV_N / 64, DIM / 64), 256, 0, stream>>>(w_qkv, wt_qkv, DIM, QKV_N, DIM, CEXP);
  transpose_w<<<dim3(DIM / 64, DIM / 64), 256, 0, stream>>>(w_out, wt_out, DIM, DIM, 0, 1.0f);
  gemm_bt_bf16<true, false><<<dim3(QKV_N / 128, ROWS / 128), 256, 0, stream>>>(
      xn, wt_qkv, nullptr, qkv, ROWS, QKV_N, DIM);
  transpose_v<<<dim3(SEQ / 64, BATCH * HEADS), 256, 0, stream>>>(qkv, vtb);
  attn_mfma<<<dim3(SEQ / 128, BATCH * HEADS), 256, 0, stream>>>(qkv, vtb, aout);
  gemm_bt_bf16<false, true><<<dim3(DIM / 128, ROWS / 128), 256, 0, stream>>>(
      aout, wt_out, b_out, outp, ROWS, DIM, DIM);
}